// Round 2
// baseline (1772.454 us; speedup 1.0000x reference)
//
// GatedTransformerXLLayer — MI355X (gfx950) — round 2: fp16-MFMA pipeline,
// tight 247 MB workspace plan (round-1 crash attributed to ws overflow).
//
// D=1024 H=16 HD=64 HID=4096 CUR=512 PREV=512 FULL=1024 BS=16

#include <hip/hip_runtime.h>
#include <stdint.h>

typedef _Float16 h16;
typedef __attribute__((ext_vector_type(8))) _Float16 f16x8;
typedef __attribute__((ext_vector_type(4))) _Float16 f16x4;
typedef __attribute__((ext_vector_type(4))) float f32x4;

enum { F_OBF = 1, F_BIAS = 2, F_RELU = 4, F_ACC = 8, F_DUAL = 16, F_SHIFT = 32 };

static __device__ __forceinline__ void gload16(const void* g, void* l) {
  __builtin_amdgcn_global_load_lds((__attribute__((address_space(1))) void*)g,
                                   (__attribute__((address_space(3))) void*)l,
                                   16, 0, 0);
}

// ---------------------------------------------------------------------------
// Generic MFMA GEMM: C = A(MxK) @ Bt(NxK)^T, fp16 in, f32 accum.
// A row-major lda (elements), Bt row-major ldb (K-contiguous).
// Batch z: base += (z/16)*s?b + (z%16)*s?h.
// ---------------------------------------------------------------------------
template <int BM, int BN, int WAVES_M, int WAVES_N, int FLAGS>
__global__ __launch_bounds__(256) void gemm_k(
    const h16* __restrict__ A, const h16* __restrict__ B,
    void* __restrict__ Cv, void* __restrict__ C2v,
    const float* __restrict__ bias, const float* __restrict__ bias2,
    int K, int lda, int ldb, int ldc,
    long sAb, long sAh, long sBb, long sBh, long sCb, long sCh) {
  constexpr int BK = 32;
  constexpr int WM = BM / WAVES_M, WN = BN / WAVES_N;
  constexpr int MF = WM / 16, NF = WN / 16;
  __shared__ h16 Al[2][BM][BK];
  __shared__ h16 Bl[2][BN][BK];

  const int tid = threadIdx.x, lane = tid & 63, wid = tid >> 6;
  const int wm = wid / WAVES_N, wn = wid % WAVES_N;
  const int z = blockIdx.z, zb = z >> 4, zh = z & 15;
  const h16* Ab = A + zb * sAb + zh * sAh + (long)blockIdx.x * BM * lda;
  const h16* Bb = B + zb * sBb + zh * sBh + (long)blockIdx.y * BN * ldb;

  const int srow = lane >> 2;            // 16 rows per load-instruction
  const int skc = (lane & 3) * 8;        // 8 fp16 (16B) per lane

  auto stage = [&](int buf, int k0) {
#pragma unroll
    for (int t = 0; t < BM / 64; ++t) {
      const int ii = wid + t * 4;
      gload16(Ab + (long)(ii * 16 + srow) * lda + k0 + skc, &Al[buf][ii * 16][0]);
    }
#pragma unroll
    for (int t = 0; t < BN / 64; ++t) {
      const int ii = wid + t * 4;
      gload16(Bb + (long)(ii * 16 + srow) * ldb + k0 + skc, &Bl[buf][ii * 16][0]);
    }
  };

  f32x4 acc[MF][NF] = {};
  const int nk = K / BK;
  const int ar = lane & 15, kc = (lane >> 4) * 8;

  stage(0, 0);
  asm volatile("s_waitcnt vmcnt(0)" ::: "memory");
  __syncthreads();
  int cur = 0;
  for (int kt = 0; kt < nk; ++kt) {
    if (kt + 1 < nk) stage(cur ^ 1, (kt + 1) * BK);
    f16x8 af[MF], bv[NF];
#pragma unroll
    for (int m = 0; m < MF; ++m)
      af[m] = *(const f16x8*)&Al[cur][wm * WM + m * 16 + ar][kc];
#pragma unroll
    for (int n = 0; n < NF; ++n)
      bv[n] = *(const f16x8*)&Bl[cur][wn * WN + n * 16 + ar][kc];
#pragma unroll
    for (int m = 0; m < MF; ++m)
#pragma unroll
      for (int n = 0; n < NF; ++n)
        acc[m][n] = __builtin_amdgcn_mfma_f32_16x16x32_f16(af[m], bv[n], acc[m][n], 0, 0, 0);
    asm volatile("s_waitcnt vmcnt(0)" ::: "memory");
    __syncthreads();
    cur ^= 1;
  }

  // epilogue: D row = (lane>>4)*4 + r (+16*m), col = lane&15 (+16*n)
  const long coff = (long)zb * sCb + (long)zh * sCh;
#pragma unroll
  for (int m = 0; m < MF; ++m) {
#pragma unroll
    for (int n = 0; n < NF; ++n) {
      const int col = blockIdx.y * BN + wn * WN + n * 16 + ar;
      float bv1 = 0.f, bv2 = 0.f;
      if (FLAGS & F_BIAS) bv1 = bias[col];
      if (FLAGS & F_DUAL) bv2 = bias2[col];
#pragma unroll
      for (int r = 0; r < 4; ++r) {
        const int row = blockIdx.x * BM + wm * WM + m * 16 + (lane >> 4) * 4 + r;
        float val = acc[m][n][r] + bv1;
        if (FLAGS & F_RELU) val = fmaxf(val, 0.f);
        if constexpr ((FLAGS & F_SHIFT) != 0) {
          // rel_shift: S[row][col + row - 511] += val  (drop if col' < 0)
          const int j = col + row - 511;
          if (j >= 0) {
            h16* p = (h16*)Cv + coff + (long)row * ldc + j;
            *p = (h16)((float)*p + val);
          }
        } else if constexpr ((FLAGS & F_ACC) != 0) {
          float* p = (float*)Cv + coff + (long)row * ldc + col;
          *p = *p + val;
        } else if constexpr ((FLAGS & F_OBF) != 0) {
          ((h16*)Cv)[coff + (long)row * ldc + col] = (h16)val;
          if constexpr ((FLAGS & F_DUAL) != 0)
            ((h16*)C2v)[coff + (long)row * ldc + col] = (h16)(acc[m][n][r] + bv2);
        } else {
          ((float*)Cv)[coff + (long)row * ldc + col] = val;
        }
      }
    }
  }
}

// ---------------------------------------------------------------------------
// Weight transpose: in f32 (K,N) -> out fp16 (N,K)
// ---------------------------------------------------------------------------
__global__ __launch_bounds__(256) void wtrans_k(const float* __restrict__ in,
                                                h16* __restrict__ out, int K, int N) {
  __shared__ float t[32][33];
  const int tx = threadIdx.x & 31, ty = threadIdx.x >> 5;
  const int n0 = blockIdx.x * 32, k0 = blockIdx.y * 32;
#pragma unroll
  for (int j = 0; j < 32; j += 8)
    t[ty + j][tx] = in[(long)(k0 + ty + j) * N + n0 + tx];
  __syncthreads();
#pragma unroll
  for (int j = 0; j < 32; j += 8)
    out[(long)(n0 + ty + j) * K + k0 + tx] = (h16)t[tx][ty + j];
}

__global__ __launch_bounds__(256) void cast_k(const float* __restrict__ in,
                                              h16* __restrict__ out, long n4) {
  const long i = (long)blockIdx.x * 256 + threadIdx.x;
  if (i >= n4) return;
  const float4 v = ((const float4*)in)[i];
  f16x4 o;
  o[0] = (h16)v.x; o[1] = (h16)v.y; o[2] = (h16)v.z; o[3] = (h16)v.w;
  ((f16x4*)out)[i] = o;
}

__global__ void addbias_k(const float* __restrict__ bq, const float* __restrict__ u,
                          const float* __restrict__ v, float* __restrict__ qu,
                          float* __restrict__ qv) {
  const int c = blockIdx.x * 256 + threadIdx.x;
  if (c < 1024) { qu[c] = bq[c] + u[c]; qv[c] = bq[c] + v[c]; }
}

__global__ __launch_bounds__(256) void zero_out_k(float* __restrict__ out, long n) {
  const long i = (long)blockIdx.x * 256 + threadIdx.x;
  if (i < n) out[i] = 0.f;
}

// LayerNorm over last dim (1024); rows < rows0 from src0, rest from src1.
__global__ __launch_bounds__(256) void ln_k(const float* __restrict__ src0,
                                            const float* __restrict__ src1, int rows0,
                                            const float* __restrict__ g,
                                            const float* __restrict__ b,
                                            h16* __restrict__ out) {
  const int row = blockIdx.x, tid = threadIdx.x;
  const float* src = (row < rows0) ? (src0 + (long)row * 1024)
                                   : (src1 + (long)(row - rows0) * 1024);
  const float4 x = ((const float4*)src)[tid];
  float s = x.x + x.y + x.z + x.w;
  float sq = x.x * x.x + x.y * x.y + x.z * x.z + x.w * x.w;
#pragma unroll
  for (int o = 32; o > 0; o >>= 1) { s += __shfl_down(s, o); sq += __shfl_down(sq, o); }
  __shared__ float red[8];
  const int lane = tid & 63, w = tid >> 6;
  if (lane == 0) { red[w] = s; red[4 + w] = sq; }
  __syncthreads();
  s = red[0] + red[1] + red[2] + red[3];
  sq = red[4] + red[5] + red[6] + red[7];
  const float mu = s * (1.f / 1024.f);
  const float inv = rsqrtf(sq * (1.f / 1024.f) - mu * mu + 1e-5f);
  const float4 gg = ((const float4*)g)[tid], bb = ((const float4*)b)[tid];
  f16x4 o;
  o[0] = (h16)((x.x - mu) * inv * gg.x + bb.x);
  o[1] = (h16)((x.y - mu) * inv * gg.y + bb.y);
  o[2] = (h16)((x.z - mu) * inv * gg.z + bb.z);
  o[3] = (h16)((x.w - mu) * inv * gg.w + bb.w);
  ((f16x4*)(out + (long)row * 1024))[tid] = o;
}

// value: kv[(j*16+b)*2048 + 1024 + h*64 + d] -> vT[(z*64+d)*1024 + j], z=b*16+h
__global__ __launch_bounds__(256) void vtrans_k(const h16* __restrict__ kv,
                                                h16* __restrict__ vT) {
  const int z = blockIdx.y, b = z >> 4, h = z & 15;
  const int j0 = blockIdx.x * 64;
  __shared__ h16 t[64][72];
  const int jj = threadIdx.x >> 3, c = threadIdx.x & 7;
#pragma unroll
  for (int half = 0; half < 2; ++half) {
    const int j = jj + half * 32;
    const f16x8 v = *(const f16x8*)(kv + ((long)(j0 + j) * 16 + b) * 2048 + 1024 + h * 64 + c * 8);
    *(f16x8*)&t[j][c * 8] = v;
  }
  __syncthreads();
#pragma unroll
  for (int half = 0; half < 2; ++half) {
    const int d = jj + half * 32;
    f16x8 o;
#pragma unroll
    for (int k = 0; k < 8; ++k) o[k] = t[c * 8 + k][d];
    *(f16x8*)(vT + ((long)z * 64 + d) * 1024 + j0 + c * 8) = o;
  }
}

// masked softmax in place over rows of S (fp16, row length 1024); row i allows
// j <= i+512; masked tail written as 0 so PV is a plain GEMM.
__global__ __launch_bounds__(256) void softmax_k(h16* __restrict__ S) {
  const long blk = blockIdx.x;
  const int i = (int)(blk & 511);
  h16* row = S + blk * 1024;
  const int tid = threadIdx.x;
  const int jmax = i + 512;
  f16x4 v = *(f16x4*)&row[tid * 4];
  float sv[4];
  float m = -1e30f;
#pragma unroll
  for (int k = 0; k < 4; ++k) {
    const int j = tid * 4 + k;
    sv[k] = (j <= jmax) ? (float)v[k] * 0.125f : -1e30f;
    m = fmaxf(m, sv[k]);
  }
  __shared__ float red[8];
  const int lane = tid & 63, w = tid >> 6;
#pragma unroll
  for (int o = 32; o > 0; o >>= 1) m = fmaxf(m, __shfl_down(m, o));
  if (lane == 0) red[w] = m;
  __syncthreads();
  m = fmaxf(fmaxf(red[0], red[1]), fmaxf(red[2], red[3]));
  float e[4], s = 0.f;
#pragma unroll
  for (int k = 0; k < 4; ++k) {
    e[k] = (sv[k] > -1e29f) ? __expf(sv[k] - m) : 0.f;
    s += e[k];
  }
#pragma unroll
  for (int o = 32; o > 0; o >>= 1) s += __shfl_down(s, o);
  if (lane == 0) red[4 + w] = s;
  __syncthreads();
  s = red[4] + red[5] + red[6] + red[7];
  const float inv = 1.f / s;
#pragma unroll
  for (int k = 0; k < 4; ++k) v[k] = (h16)(e[k] * inv);
  *(f16x4*)&row[tid * 4] = v;
}

// rx = fp16(sigmoid(T[:,0:1024]) * x); T row stride 3072
__global__ __launch_bounds__(256) void gru_rx_k(const float* __restrict__ T,
                                                const float* __restrict__ x,
                                                h16* __restrict__ rx) {
  const long i = (long)blockIdx.x * 256 + threadIdx.x;  // over 2M float4s
  const long row = i >> 8;
  const int c4 = (int)(i & 255);
  const float4 t = *((const float4*)(T + row * 3072) + c4);
  const float4 xx = ((const float4*)x)[i];
  f16x4 o;
  o[0] = (h16)(xx.x / (1.f + __expf(-t.x)));
  o[1] = (h16)(xx.y / (1.f + __expf(-t.y)));
  o[2] = (h16)(xx.z / (1.f + __expf(-t.z)));
  o[3] = (h16)(xx.w / (1.f + __expf(-t.w)));
  ((f16x4*)rx)[i] = o;
}

// o = (1-z)*x + z*tanh(Tg), z = sigmoid(Tz - bg); Tz = T[:,1024:2048], Tg = T[:,2048:3072]
__global__ __launch_bounds__(256) void gru_out_k(const float* __restrict__ T,
                                                 const float* __restrict__ x,
                                                 const float* __restrict__ bg,
                                                 float* __restrict__ outf,
                                                 h16* __restrict__ outh) {
  const long i = (long)blockIdx.x * 256 + threadIdx.x;
  const long row = i >> 8;
  const int c4 = (int)(i & 255);
  const float4 tz = *((const float4*)(T + row * 3072 + 1024) + c4);
  const float4 th = *((const float4*)(T + row * 3072 + 2048) + c4);
  const float4 xx = ((const float4*)x)[i];
  const float4 bb = ((const float4*)bg)[c4];
  float4 o;
  {
    const float z0 = 1.f / (1.f + __expf(-(tz.x - bb.x)));
    const float z1 = 1.f / (1.f + __expf(-(tz.y - bb.y)));
    const float z2 = 1.f / (1.f + __expf(-(tz.z - bb.z)));
    const float z3 = 1.f / (1.f + __expf(-(tz.w - bb.w)));
    o.x = (1.f - z0) * xx.x + z0 * tanhf(th.x);
    o.y = (1.f - z1) * xx.y + z1 * tanhf(th.y);
    o.z = (1.f - z2) * xx.z + z2 * tanhf(th.z);
    o.w = (1.f - z3) * xx.w + z3 * tanhf(th.w);
  }
  ((float4*)outf)[i] = o;
  if (outh != nullptr) {
    f16x4 oh;
    oh[0] = (h16)o.x; oh[1] = (h16)o.y; oh[2] = (h16)o.z; oh[3] = (h16)o.w;
    ((f16x4*)outh)[i] = oh;
  }
}

// ---------------------------------------------------------------------------
extern "C" void kernel_launch(void* const* d_in, const int* in_sizes, int n_in,
                              void* d_out, int out_size, void* d_ws, size_t ws_size,
                              hipStream_t stream) {
  const float* inputs = (const float*)d_in[0];   // (512,16,1024)
  const float* pos    = (const float*)d_in[1];   // (1024,1,1024)
  const float* u      = (const float*)d_in[2];   // (16,64)
  const float* v      = (const float*)d_in[3];
  const float* memory = (const float*)d_in[4];   // (512,16,1024)
  // d_in[5] = mask (recomputed analytically)
  const float* Wkv = (const float*)d_in[6];  const float* bkv = (const float*)d_in[7];
  const float* Wq  = (const float*)d_in[8];  const float* bq  = (const float*)d_in[9];
  const float* Wo  = (const float*)d_in[10]; const float* bo  = (const float*)d_in[11];
  const float* Wp  = (const float*)d_in[12]; const float* bp  = (const float*)d_in[13];
  const float* ln1_g = (const float*)d_in[14]; const float* ln1_b = (const float*)d_in[15];
  const float* ln2_g = (const float*)d_in[16]; const float* ln2_b = (const float*)d_in[17];
  const float* W1 = (const float*)d_in[18]; const float* b1 = (const float*)d_in[19];
  const float* W2 = (const float*)d_in[20]; const float* b2 = (const float*)d_in[21];
  const float* g1_W = (const float*)d_in[22]; const float* g1_U = (const float*)d_in[23];
  const float* g1_bg = (const float*)d_in[24];
  const float* g2_W = (const float*)d_in[25]; const float* g2_U = (const float*)d_in[26];
  const float* g2_bg = (const float*)d_in[27];
  (void)in_sizes; (void)n_in;

  const size_t MB = 1u << 20;
  const size_t NEEDED = 247 * MB;
  const dim3 blk(256);
  if (ws_size < NEEDED) {
    // diagnostic fallback: clean absmax failure instead of a memory fault
    zero_out_k<<<(out_size + 255) / 256, blk, 0, stream>>>((float*)d_out, out_size);
    return;
  }

  char* w = (char*)d_ws;
  // --- static plan (byte offsets, MB units). Liveness-based region reuse. ---
  h16* WoT   = (h16*)(w + 0 * MB);     // 2  MB  [P0..Wo]
  h16* W1T   = (h16*)(w + 2 * MB);     // 8  MB
  h16* W2T   = (h16*)(w + 10 * MB);    // 8  MB
  h16* g1Wb  = (h16*)(w + 18 * MB);    // 6  MB
  h16* g1Ub  = (h16*)(w + 24 * MB);    // 6  MB
  h16* g2Wb  = (h16*)(w + 30 * MB);    // 6  MB
  h16* g2Ub  = (h16*)(w + 36 * MB);    // 6  MB
  h16* WkvT  = (h16*)(w + 42 * MB);    // 4  MB
  h16* WqT   = (h16*)(w + 46 * MB);    // 2  MB
  h16* WpT   = (h16*)(w + 48 * MB);    // 2  MB
  h16* posb  = (h16*)(w + 50 * MB);    // 2  MB
  float* bias_qu = (float*)(w + 52 * MB);          // 4 KB
  float* bias_qv = (float*)(w + 52 * MB + 8192);   // 4 KB
  h16* xb    = (h16*)(w + 53 * MB);    // 16 MB  inputs as fp16
  h16* x1    = (h16*)(w + 69 * MB);    // 32 MB  ln1 out -> vT -> x2|m2, rx2
  char* Rbig =        w + 101 * MB;    // 96 MB  kvb(64)+S(32) -> Tall(f32) -> h1
  h16* qu    = (h16*)(w + 197 * MB);   // 16 MB  -> a1 -> o1f(lo)
  h16* qv    = (h16*)(w + 213 * MB);   // 16 MB  -> rx1 -> o1f(hi)
  h16* rb    = (h16*)(w + 229 * MB);   // 2  MB
  h16* attn  = (h16*)(w + 231 * MB);   // 16 MB  -> o1b
  // total: 247 MB

  h16*   kvb  = (h16*)Rbig;                   // 64 MB (key|value interleaved)
  h16*   S    = (h16*)(Rbig + 64 * MB);       // 32 MB (2-batch attn groups)
  float* Tall = (float*)Rbig;                 // 96 MB GRU pre-activations
  h16*   h1   = (h16*)Rbig;                   // 67 MB MLP hidden
  h16*   vT   = x1;                           // 32 MB (x1 dead after q GEMM)
  h16*   a1   = qu;
  h16*   rx1  = qv;
  float* o1f  = (float*)qu;                   // 32 MB spans qu+qv (both dead)
  h16*   o1b  = attn;                         // attn dead after Wo GEMM
  h16*   x2   = x1;                           // first 16 MB (vT dead post-attn)
  h16*   m2   = x1 + 8L * 1024 * 1024;        // second 16 MB
  h16*   rx2  = x1;                           // x2 slot, dead after W1 GEMM

  // ---- weight prep ----
  wtrans_k<<<dim3(64, 32), blk, 0, stream>>>(Wkv, WkvT, 1024, 2048);
  wtrans_k<<<dim3(32, 32), blk, 0, stream>>>(Wq, WqT, 1024, 1024);
  wtrans_k<<<dim3(32, 32), blk, 0, stream>>>(Wo, WoT, 1024, 1024);
  wtrans_k<<<dim3(32, 32), blk, 0, stream>>>(Wp, WpT, 1024, 1024);
  wtrans_k<<<dim3(128, 32), blk, 0, stream>>>(W1, W1T, 1024, 4096);
  wtrans_k<<<dim3(32, 128), blk, 0, stream>>>(W2, W2T, 4096, 1024);
  cast_k<<<3072, blk, 0, stream>>>(g1_W, g1Wb, 786432);  // y@W.T: already (N,K)
  cast_k<<<3072, blk, 0, stream>>>(g1_U, g1Ub, 786432);
  cast_k<<<3072, blk, 0, stream>>>(g2_W, g2Wb, 786432);
  cast_k<<<3072, blk, 0, stream>>>(g2_U, g2Ub, 786432);
  cast_k<<<1024, blk, 0, stream>>>(pos, posb, 262144);
  cast_k<<<8192, blk, 0, stream>>>(inputs, xb, 2097152);
  addbias_k<<<4, blk, 0, stream>>>(bq, u, v, bias_qu, bias_qv);

  // ---- ln1 over concat(memory, inputs) ----
  ln_k<<<16384, blk, 0, stream>>>(memory, inputs, 8192, ln1_g, ln1_b, x1);

  // ---- projections ----
  gemm_k<128, 128, 2, 2, F_OBF | F_BIAS><<<dim3(128, 16, 1), blk, 0, stream>>>(
      x1, WkvT, kvb, nullptr, bkv, nullptr, 1024, 1024, 1024, 2048, 0, 0, 0, 0, 0, 0);
  gemm_k<128, 128, 2, 2, F_OBF | F_BIAS | F_DUAL><<<dim3(64, 8, 1), blk, 0, stream>>>(
      x1 + 8192L * 1024, WqT, qu, qv, bias_qu, bias_qv, 1024, 1024, 1024, 1024, 0, 0, 0, 0, 0, 0);
  gemm_k<128, 128, 2, 2, F_OBF | F_BIAS><<<dim3(8, 8, 1), blk, 0, stream>>>(
      posb, WpT, rb, nullptr, bp, nullptr, 1024, 1024, 1024, 1024, 0, 0, 0, 0, 0, 0);
  vtrans_k<<<dim3(16, 256), blk, 0, stream>>>(kvb, vT);  // after q GEMM (x1 dead)

  // ---- attention, 8 groups of 2 batches (z local = b_local*16 + h) ----
  for (int g = 0; g < 8; ++g) {
    // content: (q+u) @ key^T
    gemm_k<128, 128, 2, 2, F_OBF><<<dim3(4, 8, 32), blk, 0, stream>>>(
        qu + (long)g * 2 * 1024, kvb + (long)g * 2 * 2048, S, nullptr, nullptr, nullptr,
        64, 16384, 32768, 1024,
        1024, 64, 2048, 64, 8388608, 524288);
    // position: (q+v) @ r^T, rel-shift fused (RMW into S)
    gemm_k<128, 128, 2, 2, F_SHIFT><<<dim3(4, 8, 32), blk, 0, stream>>>(
        qv + (long)g * 2 * 1024, rb, S, nullptr, nullptr, nullptr,
        64, 16384, 1024, 1024,
        1024, 64, 0, 64, 8388608, 524288);
    softmax_k<<<16384, blk, 0, stream>>>(S);
    // PV: p @ vT^T -> attn (cur,bs,H*HD)
    gemm_k<128, 64, 4, 1, F_OBF><<<dim3(4, 1, 32), blk, 0, stream>>>(
        S, vT + (long)g * 2097152, attn + (long)g * 2 * 1024, nullptr, nullptr, nullptr,
        1024, 1024, 1024, 16384,
        8388608, 524288, 1048576, 65536, 1024, 64);
  }

  // ---- output projection + relu -> a1 ----
  gemm_k<128, 128, 2, 2, F_OBF | F_BIAS | F_RELU><<<dim3(64, 8, 1), blk, 0, stream>>>(
      attn, WoT, a1, nullptr, bo, nullptr, 1024, 1024, 1024, 1024, 0, 0, 0, 0, 0, 0);

  // ---- GRU gate 1: x = inputs, y = a1 ----
  gemm_k<128, 128, 2, 2, 0><<<dim3(64, 24, 1), blk, 0, stream>>>(
      a1, g1Wb, Tall, nullptr, nullptr, nullptr, 1024, 1024, 1024, 3072, 0, 0, 0, 0, 0, 0);
  gemm_k<128, 128, 2, 2, F_ACC><<<dim3(64, 16, 1), blk, 0, stream>>>(
      xb, g1Ub, Tall, nullptr, nullptr, nullptr, 1024, 1024, 1024, 3072, 0, 0, 0, 0, 0, 0);
  gru_rx_k<<<8192, blk, 0, stream>>>(Tall, inputs, rx1);
  gemm_k<128, 128, 2, 2, F_ACC><<<dim3(64, 8, 1), blk, 0, stream>>>(
      rx1, g1Ub + 2L * 1024 * 1024, Tall + 2048, nullptr, nullptr, nullptr,
      1024, 1024, 1024, 3072, 0, 0, 0, 0, 0, 0);
  gru_out_k<<<8192, blk, 0, stream>>>(Tall, inputs, g1_bg, o1f, o1b);

  // ---- ln2 + MLP ----
  ln_k<<<8192, blk, 0, stream>>>(o1f, o1f, 8192, ln2_g, ln2_b, x2);
  gemm_k<128, 128, 2, 2, F_OBF | F_BIAS | F_RELU><<<dim3(64, 32, 1), blk, 0, stream>>>(
      x2, W1T, h1, nullptr, b1, nullptr, 1024, 1024, 1024, 4096, 0, 0, 0, 0, 0, 0);
  gemm_k<128, 128, 2, 2, F_OBF | F_BIAS | F_RELU><<<dim3(64, 8, 1), blk, 0, stream>>>(
      h1, W2T, m2, nullptr, b2, nullptr, 4096, 4096, 4096, 1024, 0, 0, 0, 0, 0, 0);

  // ---- GRU gate 2: x = o1, y = m2 -> d_out ----
  gemm_k<128, 128, 2, 2, 0><<<dim3(64, 24, 1), blk, 0, stream>>>(
      m2, g2Wb, Tall, nullptr, nullptr, nullptr, 1024, 1024, 1024, 3072, 0, 0, 0, 0, 0, 0);
  gemm_k<128, 128, 2, 2, F_ACC><<<dim3(64, 16, 1), blk, 0, stream>>>(
      o1b, g2Ub, Tall, nullptr, nullptr, nullptr, 1024, 1024, 1024, 3072, 0, 0, 0, 0, 0, 0);
  gru_rx_k<<<8192, blk, 0, stream>>>(Tall, o1f, rx2);
  gemm_k<128, 128, 2, 2, F_ACC><<<dim3(64, 8, 1), blk, 0, stream>>>(
      rx2, g2Ub + 2L * 1024 * 1024, Tall + 2048, nullptr, nullptr, nullptr,
      1024, 1024, 1024, 3072, 0, 0, 0, 0, 0, 0);
  gru_out_k<<<8192, blk, 0, stream>>>(Tall, o1f, g2_bg, (float*)d_out, nullptr);
}

// Round 3
// 1700.835 us; speedup vs baseline: 1.0421x; 1.0421x over previous
//
// GatedTransformerXLLayer — MI355X (gfx950) — round 3:
//   + T2 LDS XOR-swizzle in gemm_k (r2: 8.4M bank conflicts, MfmaUtil 24%)
//     pre-swizzled global source (rule 21) + swizzled ds_read, LDS dest linear
//   + rel-shift: position GEMM writes shifted (pure W), content GEMM does
//     coalesced h16 RMW-add (was: scattered RMW in position epilogue)
//
// D=1024 H=16 HD=64 HID=4096 CUR=512 PREV=512 FULL=1024 BS=16

#include <hip/hip_runtime.h>
#include <stdint.h>

typedef _Float16 h16;
typedef __attribute__((ext_vector_type(8))) _Float16 f16x8;
typedef __attribute__((ext_vector_type(4))) _Float16 f16x4;
typedef __attribute__((ext_vector_type(4))) float f32x4;

enum { F_OBF = 1, F_BIAS = 2, F_RELU = 4, F_ACC = 8, F_DUAL = 16, F_SHIFT = 32, F_ACCH = 64 };

static __device__ __forceinline__ void gload16(const void* g, void* l) {
  __builtin_amdgcn_global_load_lds((__attribute__((address_space(1))) void*)g,
                                   (__attribute__((address_space(3))) void*)l,
                                   16, 0, 0);
}

// ---------------------------------------------------------------------------
// Generic MFMA GEMM: C = A(MxK) @ Bt(NxK)^T, fp16 in, f32 accum.
// LDS tile [R][32] fp16 (64B rows, 4 16B slots). Swizzle: physical slot =
// logical slot ^ ((row>>1)&3). global_load_lds writes linearly (lane -> 16B
// slot), so the SOURCE column is pre-permuted; reads apply the same XOR.
// ---------------------------------------------------------------------------
template <int BM, int BN, int WAVES_M, int WAVES_N, int FLAGS>
__global__ __launch_bounds__(256) void gemm_k(
    const h16* __restrict__ A, const h16* __restrict__ B,
    void* __restrict__ Cv, void* __restrict__ C2v,
    const float* __restrict__ bias, const float* __restrict__ bias2,
    int K, int lda, int ldb, int ldc,
    long sAb, long sAh, long sBb, long sBh, long sCb, long sCh) {
  constexpr int BK = 32;
  constexpr int WM = BM / WAVES_M, WN = BN / WAVES_N;
  constexpr int MF = WM / 16, NF = WN / 16;
  __shared__ h16 Al[2][BM][BK];
  __shared__ h16 Bl[2][BN][BK];

  const int tid = threadIdx.x, lane = tid & 63, wid = tid >> 6;
  const int wm = wid / WAVES_N, wn = wid % WAVES_N;
  const int z = blockIdx.z, zb = z >> 4, zh = z & 15;
  const h16* Ab = A + zb * sAb + zh * sAh + (long)blockIdx.x * BM * lda;
  const h16* Bb = B + zb * sBb + zh * sBh + (long)blockIdx.y * BN * ldb;

  const int srow = lane >> 2;                              // row within 16-row chunk
  const int skc = (((lane & 3) ^ ((lane >> 3) & 3)) * 8);  // pre-swizzled source slot

  auto stage = [&](int buf, int k0) {
#pragma unroll
    for (int t = 0; t < BM / 64; ++t) {
      const int ii = wid + t * 4;
      gload16(Ab + (long)(ii * 16 + srow) * lda + k0 + skc, &Al[buf][ii * 16][0]);
    }
#pragma unroll
    for (int t = 0; t < BN / 64; ++t) {
      const int ii = wid + t * 4;
      gload16(Bb + (long)(ii * 16 + srow) * ldb + k0 + skc, &Bl[buf][ii * 16][0]);
    }
  };

  f32x4 acc[MF][NF] = {};
  const int nk = K / BK;
  const int ar = lane & 15, ls = lane >> 4;  // fragment row, logical K-slot

  stage(0, 0);
  asm volatile("s_waitcnt vmcnt(0)" ::: "memory");
  __syncthreads();
  int cur = 0;
  for (int kt = 0; kt < nk; ++kt) {
    if (kt + 1 < nk) stage(cur ^ 1, (kt + 1) * BK);
    f16x8 af[MF], bv[NF];
#pragma unroll
    for (int m = 0; m < MF; ++m) {
      const int R = wm * WM + m * 16 + ar;
      af[m] = *(const f16x8*)&Al[cur][R][(ls ^ ((R >> 1) & 3)) * 8];
    }
#pragma unroll
    for (int n = 0; n < NF; ++n) {
      const int R = wn * WN + n * 16 + ar;
      bv[n] = *(const f16x8*)&Bl[cur][R][(ls ^ ((R >> 1) & 3)) * 8];
    }
#pragma unroll
    for (int m = 0; m < MF; ++m)
#pragma unroll
      for (int n = 0; n < NF; ++n)
        acc[m][n] = __builtin_amdgcn_mfma_f32_16x16x32_f16(af[m], bv[n], acc[m][n], 0, 0, 0);
    asm volatile("s_waitcnt vmcnt(0)" ::: "memory");
    __syncthreads();
    cur ^= 1;
  }

  // epilogue: D row = (lane>>4)*4 + r (+16*m), col = lane&15 (+16*n)
  const long coff = (long)zb * sCb + (long)zh * sCh;
#pragma unroll
  for (int m = 0; m < MF; ++m) {
#pragma unroll
    for (int n = 0; n < NF; ++n) {
      const int col = blockIdx.y * BN + wn * WN + n * 16 + ar;
      float bv1 = 0.f, bv2 = 0.f;
      if (FLAGS & F_BIAS) bv1 = bias[col];
      if (FLAGS & F_DUAL) bv2 = bias2[col];
#pragma unroll
      for (int r = 0; r < 4; ++r) {
        const int row = blockIdx.x * BM + wm * WM + m * 16 + (lane >> 4) * 4 + r;
        float val = acc[m][n][r] + bv1;
        if (FLAGS & F_RELU) val = fmaxf(val, 0.f);
        if constexpr ((FLAGS & F_SHIFT) != 0) {
          // rel_shift: S[row][col + row - 511] = val (pure write; covers the
          // whole unmasked region exactly once, masked region left stale)
          const int j = col + row - 511;
          if (j >= 0) ((h16*)Cv)[coff + (long)row * ldc + j] = (h16)val;
        } else if constexpr ((FLAGS & F_ACCH) != 0) {
          h16* p = (h16*)Cv + coff + (long)row * ldc + col;
          *p = (h16)((float)*p + val);
        } else if constexpr ((FLAGS & F_ACC) != 0) {
          float* p = (float*)Cv + coff + (long)row * ldc + col;
          *p = *p + val;
        } else if constexpr ((FLAGS & F_OBF) != 0) {
          ((h16*)Cv)[coff + (long)row * ldc + col] = (h16)val;
          if constexpr ((FLAGS & F_DUAL) != 0)
            ((h16*)C2v)[coff + (long)row * ldc + col] = (h16)(acc[m][n][r] + bv2);
        } else {
          ((float*)Cv)[coff + (long)row * ldc + col] = val;
        }
      }
    }
  }
}

// ---------------------------------------------------------------------------
// Weight transpose: in f32 (K,N) -> out fp16 (N,K)
// ---------------------------------------------------------------------------
__global__ __launch_bounds__(256) void wtrans_k(const float* __restrict__ in,
                                                h16* __restrict__ out, int K, int N) {
  __shared__ float t[32][33];
  const int tx = threadIdx.x & 31, ty = threadIdx.x >> 5;
  const int n0 = blockIdx.x * 32, k0 = blockIdx.y * 32;
#pragma unroll
  for (int j = 0; j < 32; j += 8)
    t[ty + j][tx] = in[(long)(k0 + ty + j) * N + n0 + tx];
  __syncthreads();
#pragma unroll
  for (int j = 0; j < 32; j += 8)
    out[(long)(n0 + ty + j) * K + k0 + tx] = (h16)t[tx][ty + j];
}

__global__ __launch_bounds__(256) void cast_k(const float* __restrict__ in,
                                              h16* __restrict__ out, long n4) {
  const long i = (long)blockIdx.x * 256 + threadIdx.x;
  if (i >= n4) return;
  const float4 v = ((const float4*)in)[i];
  f16x4 o;
  o[0] = (h16)v.x; o[1] = (h16)v.y; o[2] = (h16)v.z; o[3] = (h16)v.w;
  ((f16x4*)out)[i] = o;
}

__global__ void addbias_k(const float* __restrict__ bq, const float* __restrict__ u,
                          const float* __restrict__ v, float* __restrict__ qu,
                          float* __restrict__ qv) {
  const int c = blockIdx.x * 256 + threadIdx.x;
  if (c < 1024) { qu[c] = bq[c] + u[c]; qv[c] = bq[c] + v[c]; }
}

__global__ __launch_bounds__(256) void zero_out_k(float* __restrict__ out, long n) {
  const long i = (long)blockIdx.x * 256 + threadIdx.x;
  if (i < n) out[i] = 0.f;
}

// LayerNorm over last dim (1024); rows < rows0 from src0, rest from src1.
__global__ __launch_bounds__(256) void ln_k(const float* __restrict__ src0,
                                            const float* __restrict__ src1, int rows0,
                                            const float* __restrict__ g,
                                            const float* __restrict__ b,
                                            h16* __restrict__ out) {
  const int row = blockIdx.x, tid = threadIdx.x;
  const float* src = (row < rows0) ? (src0 + (long)row * 1024)
                                   : (src1 + (long)(row - rows0) * 1024);
  const float4 x = ((const float4*)src)[tid];
  float s = x.x + x.y + x.z + x.w;
  float sq = x.x * x.x + x.y * x.y + x.z * x.z + x.w * x.w;
#pragma unroll
  for (int o = 32; o > 0; o >>= 1) { s += __shfl_down(s, o); sq += __shfl_down(sq, o); }
  __shared__ float red[8];
  const int lane = tid & 63, w = tid >> 6;
  if (lane == 0) { red[w] = s; red[4 + w] = sq; }
  __syncthreads();
  s = red[0] + red[1] + red[2] + red[3];
  sq = red[4] + red[5] + red[6] + red[7];
  const float mu = s * (1.f / 1024.f);
  const float inv = rsqrtf(sq * (1.f / 1024.f) - mu * mu + 1e-5f);
  const float4 gg = ((const float4*)g)[tid], bb = ((const float4*)b)[tid];
  f16x4 o;
  o[0] = (h16)((x.x - mu) * inv * gg.x + bb.x);
  o[1] = (h16)((x.y - mu) * inv * gg.y + bb.y);
  o[2] = (h16)((x.z - mu) * inv * gg.z + bb.z);
  o[3] = (h16)((x.w - mu) * inv * gg.w + bb.w);
  ((f16x4*)(out + (long)row * 1024))[tid] = o;
}

// value: kv[(j*16+b)*2048 + 1024 + h*64 + d] -> vT[(z*64+d)*1024 + j], z=b*16+h
__global__ __launch_bounds__(256) void vtrans_k(const h16* __restrict__ kv,
                                                h16* __restrict__ vT) {
  const int z = blockIdx.y, b = z >> 4, h = z & 15;
  const int j0 = blockIdx.x * 64;
  __shared__ h16 t[64][72];
  const int jj = threadIdx.x >> 3, c = threadIdx.x & 7;
#pragma unroll
  for (int half = 0; half < 2; ++half) {
    const int j = jj + half * 32;
    const f16x8 v = *(const f16x8*)(kv + ((long)(j0 + j) * 16 + b) * 2048 + 1024 + h * 64 + c * 8);
    *(f16x8*)&t[j][c * 8] = v;
  }
  __syncthreads();
#pragma unroll
  for (int half = 0; half < 2; ++half) {
    const int d = jj + half * 32;
    f16x8 o;
#pragma unroll
    for (int k = 0; k < 8; ++k) o[k] = t[c * 8 + k][d];
    *(f16x8*)(vT + ((long)z * 64 + d) * 1024 + j0 + c * 8) = o;
  }
}

// masked softmax in place over rows of S (fp16, row length 1024); row i allows
// j <= i+512; masked tail written as 0 so PV is a plain GEMM.
__global__ __launch_bounds__(256) void softmax_k(h16* __restrict__ S) {
  const long blk = blockIdx.x;
  const int i = (int)(blk & 511);
  h16* row = S + blk * 1024;
  const int tid = threadIdx.x;
  const int jmax = i + 512;
  f16x4 v = *(f16x4*)&row[tid * 4];
  float sv[4];
  float m = -1e30f;
#pragma unroll
  for (int k = 0; k < 4; ++k) {
    const int j = tid * 4 + k;
    sv[k] = (j <= jmax) ? (float)v[k] * 0.125f : -1e30f;
    m = fmaxf(m, sv[k]);
  }
  __shared__ float red[8];
  const int lane = tid & 63, w = tid >> 6;
#pragma unroll
  for (int o = 32; o > 0; o >>= 1) m = fmaxf(m, __shfl_down(m, o));
  if (lane == 0) red[w] = m;
  __syncthreads();
  m = fmaxf(fmaxf(red[0], red[1]), fmaxf(red[2], red[3]));
  float e[4], s = 0.f;
#pragma unroll
  for (int k = 0; k < 4; ++k) {
    e[k] = (sv[k] > -1e29f) ? __expf(sv[k] - m) : 0.f;
    s += e[k];
  }
#pragma unroll
  for (int o = 32; o > 0; o >>= 1) s += __shfl_down(s, o);
  if (lane == 0) red[4 + w] = s;
  __syncthreads();
  s = red[4] + red[5] + red[6] + red[7];
  const float inv = 1.f / s;
#pragma unroll
  for (int k = 0; k < 4; ++k) v[k] = (h16)(e[k] * inv);
  *(f16x4*)&row[tid * 4] = v;
}

// rx = fp16(sigmoid(T[:,0:1024]) * x); T row stride 3072
__global__ __launch_bounds__(256) void gru_rx_k(const float* __restrict__ T,
                                                const float* __restrict__ x,
                                                h16* __restrict__ rx) {
  const long i = (long)blockIdx.x * 256 + threadIdx.x;  // over 2M float4s
  const long row = i >> 8;
  const int c4 = (int)(i & 255);
  const float4 t = *((const float4*)(T + row * 3072) + c4);
  const float4 xx = ((const float4*)x)[i];
  f16x4 o;
  o[0] = (h16)(xx.x / (1.f + __expf(-t.x)));
  o[1] = (h16)(xx.y / (1.f + __expf(-t.y)));
  o[2] = (h16)(xx.z / (1.f + __expf(-t.z)));
  o[3] = (h16)(xx.w / (1.f + __expf(-t.w)));
  ((f16x4*)rx)[i] = o;
}

// o = (1-z)*x + z*tanh(Tg), z = sigmoid(Tz - bg); Tz = T[:,1024:2048], Tg = T[:,2048:3072]
__global__ __launch_bounds__(256) void gru_out_k(const float* __restrict__ T,
                                                 const float* __restrict__ x,
                                                 const float* __restrict__ bg,
                                                 float* __restrict__ outf,
                                                 h16* __restrict__ outh) {
  const long i = (long)blockIdx.x * 256 + threadIdx.x;
  const long row = i >> 8;
  const int c4 = (int)(i & 255);
  const float4 tz = *((const float4*)(T + row * 3072 + 1024) + c4);
  const float4 th = *((const float4*)(T + row * 3072 + 2048) + c4);
  const float4 xx = ((const float4*)x)[i];
  const float4 bb = ((const float4*)bg)[c4];
  float4 o;
  {
    const float z0 = 1.f / (1.f + __expf(-(tz.x - bb.x)));
    const float z1 = 1.f / (1.f + __expf(-(tz.y - bb.y)));
    const float z2 = 1.f / (1.f + __expf(-(tz.z - bb.z)));
    const float z3 = 1.f / (1.f + __expf(-(tz.w - bb.w)));
    o.x = (1.f - z0) * xx.x + z0 * tanhf(th.x);
    o.y = (1.f - z1) * xx.y + z1 * tanhf(th.y);
    o.z = (1.f - z2) * xx.z + z2 * tanhf(th.z);
    o.w = (1.f - z3) * xx.w + z3 * tanhf(th.w);
  }
  ((float4*)outf)[i] = o;
  if (outh != nullptr) {
    f16x4 oh;
    oh[0] = (h16)o.x; oh[1] = (h16)o.y; oh[2] = (h16)o.z; oh[3] = (h16)o.w;
    ((f16x4*)outh)[i] = oh;
  }
}

// ---------------------------------------------------------------------------
extern "C" void kernel_launch(void* const* d_in, const int* in_sizes, int n_in,
                              void* d_out, int out_size, void* d_ws, size_t ws_size,
                              hipStream_t stream) {
  const float* inputs = (const float*)d_in[0];   // (512,16,1024)
  const float* pos    = (const float*)d_in[1];   // (1024,1,1024)
  const float* u      = (const float*)d_in[2];   // (16,64)
  const float* v      = (const float*)d_in[3];
  const float* memory = (const float*)d_in[4];   // (512,16,1024)
  // d_in[5] = mask (recomputed analytically)
  const float* Wkv = (const float*)d_in[6];  const float* bkv = (const float*)d_in[7];
  const float* Wq  = (const float*)d_in[8];  const float* bq  = (const float*)d_in[9];
  const float* Wo  = (const float*)d_in[10]; const float* bo  = (const float*)d_in[11];
  const float* Wp  = (const float*)d_in[12]; const float* bp  = (const float*)d_in[13];
  const float* ln1_g = (const float*)d_in[14]; const float* ln1_b = (const float*)d_in[15];
  const float* ln2_g = (const float*)d_in[16]; const float* ln2_b = (const float*)d_in[17];
  const float* W1 = (const float*)d_in[18]; const float* b1 = (const float*)d_in[19];
  const float* W2 = (const float*)d_in[20]; const float* b2 = (const float*)d_in[21];
  const float* g1_W = (const float*)d_in[22]; const float* g1_U = (const float*)d_in[23];
  const float* g1_bg = (const float*)d_in[24];
  const float* g2_W = (const float*)d_in[25]; const float* g2_U = (const float*)d_in[26];
  const float* g2_bg = (const float*)d_in[27];
  (void)in_sizes; (void)n_in;

  const size_t MB = 1u << 20;
  const size_t NEEDED = 247 * MB;
  const dim3 blk(256);
  if (ws_size < NEEDED) {
    // diagnostic fallback: clean absmax failure instead of a memory fault
    zero_out_k<<<(out_size + 255) / 256, blk, 0, stream>>>((float*)d_out, out_size);
    return;
  }

  char* w = (char*)d_ws;
  // --- static plan (byte offsets, MB units). Liveness-based region reuse. ---
  h16* WoT   = (h16*)(w + 0 * MB);     // 2  MB  [P0..Wo]
  h16* W1T   = (h16*)(w + 2 * MB);     // 8  MB
  h16* W2T   = (h16*)(w + 10 * MB);    // 8  MB
  h16* g1Wb  = (h16*)(w + 18 * MB);    // 6  MB
  h16* g1Ub  = (h16*)(w + 24 * MB);    // 6  MB
  h16* g2Wb  = (h16*)(w + 30 * MB);    // 6  MB
  h16* g2Ub  = (h16*)(w + 36 * MB);    // 6  MB
  h16* WkvT  = (h16*)(w + 42 * MB);    // 4  MB
  h16* WqT   = (h16*)(w + 46 * MB);    // 2  MB
  h16* WpT   = (h16*)(w + 48 * MB);    // 2  MB
  h16* posb  = (h16*)(w + 50 * MB);    // 2  MB
  float* bias_qu = (float*)(w + 52 * MB);          // 4 KB
  float* bias_qv = (float*)(w + 52 * MB + 8192);   // 4 KB
  h16* xb    = (h16*)(w + 53 * MB);    // 16 MB  inputs as fp16
  h16* x1    = (h16*)(w + 69 * MB);    // 32 MB  ln1 out -> vT -> x2|m2, rx2
  char* Rbig =        w + 101 * MB;    // 96 MB  kvb(64)+S(32) -> Tall(f32) -> h1
  h16* qu    = (h16*)(w + 197 * MB);   // 16 MB  -> a1 -> o1f(lo)
  h16* qv    = (h16*)(w + 213 * MB);   // 16 MB  -> rx1 -> o1f(hi)
  h16* rb    = (h16*)(w + 229 * MB);   // 2  MB
  h16* attn  = (h16*)(w + 231 * MB);   // 16 MB  -> o1b
  // total: 247 MB

  h16*   kvb  = (h16*)Rbig;                   // 64 MB (key|value interleaved)
  h16*   S    = (h16*)(Rbig + 64 * MB);       // 32 MB (2-batch attn groups)
  float* Tall = (float*)Rbig;                 // 96 MB GRU pre-activations
  h16*   h1   = (h16*)Rbig;                   // 67 MB MLP hidden
  h16*   vT   = x1;                           // 32 MB (x1 dead after q GEMM)
  h16*   a1   = qu;
  h16*   rx1  = qv;
  float* o1f  = (float*)qu;                   // 32 MB spans qu+qv (both dead)
  h16*   o1b  = attn;                         // attn dead after Wo GEMM
  h16*   x2   = x1;                           // first 16 MB (vT dead post-attn)
  h16*   m2   = x1 + 8L * 1024 * 1024;        // second 16 MB
  h16*   rx2  = x1;                           // x2 slot, dead after W1 GEMM

  // ---- weight prep ----
  wtrans_k<<<dim3(64, 32), blk, 0, stream>>>(Wkv, WkvT, 1024, 2048);
  wtrans_k<<<dim3(32, 32), blk, 0, stream>>>(Wq, WqT, 1024, 1024);
  wtrans_k<<<dim3(32, 32), blk, 0, stream>>>(Wo, WoT, 1024, 1024);
  wtrans_k<<<dim3(32, 32), blk, 0, stream>>>(Wp, WpT, 1024, 1024);
  wtrans_k<<<dim3(128, 32), blk, 0, stream>>>(W1, W1T, 1024, 4096);
  wtrans_k<<<dim3(32, 128), blk, 0, stream>>>(W2, W2T, 4096, 1024);
  cast_k<<<3072, blk, 0, stream>>>(g1_W, g1Wb, 786432);  // y@W.T: already (N,K)
  cast_k<<<3072, blk, 0, stream>>>(g1_U, g1Ub, 786432);
  cast_k<<<3072, blk, 0, stream>>>(g2_W, g2Wb, 786432);
  cast_k<<<3072, blk, 0, stream>>>(g2_U, g2Ub, 786432);
  cast_k<<<1024, blk, 0, stream>>>(pos, posb, 262144);
  cast_k<<<8192, blk, 0, stream>>>(inputs, xb, 2097152);
  addbias_k<<<4, blk, 0, stream>>>(bq, u, v, bias_qu, bias_qv);

  // ---- ln1 over concat(memory, inputs) ----
  ln_k<<<16384, blk, 0, stream>>>(memory, inputs, 8192, ln1_g, ln1_b, x1);

  // ---- projections ----
  gemm_k<128, 128, 2, 2, F_OBF | F_BIAS><<<dim3(128, 16, 1), blk, 0, stream>>>(
      x1, WkvT, kvb, nullptr, bkv, nullptr, 1024, 1024, 1024, 2048, 0, 0, 0, 0, 0, 0);
  gemm_k<128, 128, 2, 2, F_OBF | F_BIAS | F_DUAL><<<dim3(64, 8, 1), blk, 0, stream>>>(
      x1 + 8192L * 1024, WqT, qu, qv, bias_qu, bias_qv, 1024, 1024, 1024, 1024, 0, 0, 0, 0, 0, 0);
  gemm_k<128, 128, 2, 2, F_OBF | F_BIAS><<<dim3(8, 8, 1), blk, 0, stream>>>(
      posb, WpT, rb, nullptr, bp, nullptr, 1024, 1024, 1024, 1024, 0, 0, 0, 0, 0, 0);
  vtrans_k<<<dim3(16, 256), blk, 0, stream>>>(kvb, vT);  // after q GEMM (x1 dead)

  // ---- attention, 8 groups of 2 batches (z local = b_local*16 + h) ----
  for (int g = 0; g < 8; ++g) {
    // position: (q+v) @ r^T, written at rel-shifted columns (covers unmasked region)
    gemm_k<128, 128, 2, 2, F_SHIFT><<<dim3(4, 8, 32), blk, 0, stream>>>(
        qv + (long)g * 2 * 1024, rb, S, nullptr, nullptr, nullptr,
        64, 16384, 1024, 1024,
        1024, 64, 0, 64, 8388608, 524288);
    // content: (q+u) @ key^T, coalesced h16 add into S
    gemm_k<128, 128, 2, 2, F_ACCH><<<dim3(4, 8, 32), blk, 0, stream>>>(
        qu + (long)g * 2 * 1024, kvb + (long)g * 2 * 2048, S, nullptr, nullptr, nullptr,
        64, 16384, 32768, 1024,
        1024, 64, 2048, 64, 8388608, 524288);
    softmax_k<<<16384, blk, 0, stream>>>(S);
    // PV: p @ vT^T -> attn (cur,bs,H*HD)
    gemm_k<128, 64, 4, 1, F_OBF><<<dim3(4, 1, 32), blk, 0, stream>>>(
        S, vT + (long)g * 2097152, attn + (long)g * 2 * 1024, nullptr, nullptr, nullptr,
        1024, 1024, 1024, 16384,
        8388608, 524288, 1048576, 65536, 1024, 64);
  }

  // ---- output projection + relu -> a1 ----
  gemm_k<128, 128, 2, 2, F_OBF | F_BIAS | F_RELU><<<dim3(64, 8, 1), blk, 0, stream>>>(
      attn, WoT, a1, nullptr, bo, nullptr, 1024, 1024, 1024, 1024, 0, 0, 0, 0, 0, 0);

  // ---- GRU gate 1: x = inputs, y = a1 ----
  gemm_k<128, 128, 2, 2, 0><<<dim3(64, 24, 1), blk, 0, stream>>>(
      a1, g1Wb, Tall, nullptr, nullptr, nullptr, 1024, 1024, 1024, 3072, 0, 0, 0, 0, 0, 0);
  gemm_k<128, 128, 2, 2, F_ACC><<<dim3(64, 16, 1), blk, 0, stream>>>(
      xb, g1Ub, Tall, nullptr, nullptr, nullptr, 1024, 1024, 1024, 3072, 0, 0, 0, 0, 0, 0);
  gru_rx_k<<<8192, blk, 0, stream>>>(Tall, inputs, rx1);
  gemm_k<128, 128, 2, 2, F_ACC><<<dim3(64, 8, 1), blk, 0, stream>>>(
      rx1, g1Ub + 2L * 1024 * 1024, Tall + 2048, nullptr, nullptr, nullptr,
      1024, 1024, 1024, 3072, 0, 0, 0, 0, 0, 0);
  gru_out_k<<<8192, blk, 0, stream>>>(Tall, inputs, g1_bg, o1f, o1b);

  // ---- ln2 + MLP ----
  ln_k<<<8192, blk, 0, stream>>>(o1f, o1f, 8192, ln2_g, ln2_b, x2);
  gemm_k<128, 128, 2, 2, F_OBF | F_BIAS | F_RELU><<<dim3(64, 32, 1), blk, 0, stream>>>(
      x2, W1T, h1, nullptr, b1, nullptr, 1024, 1024, 1024, 4096, 0, 0, 0, 0, 0, 0);
  gemm_k<128, 128, 2, 2, F_OBF | F_BIAS | F_RELU><<<dim3(64, 8, 1), blk, 0, stream>>>(
      h1, W2T, m2, nullptr, b2, nullptr, 4096, 4096, 4096, 1024, 0, 0, 0, 0, 0, 0);

  // ---- GRU gate 2: x = o1, y = m2 -> d_out ----
  gemm_k<128, 128, 2, 2, 0><<<dim3(64, 24, 1), blk, 0, stream>>>(
      m2, g2Wb, Tall, nullptr, nullptr, nullptr, 1024, 1024, 1024, 3072, 0, 0, 0, 0, 0, 0);
  gemm_k<128, 128, 2, 2, F_ACC><<<dim3(64, 16, 1), blk, 0, stream>>>(
      o1b, g2Ub, Tall, nullptr, nullptr, nullptr, 1024, 1024, 1024, 3072, 0, 0, 0, 0, 0, 0);
  gru_rx_k<<<8192, blk, 0, stream>>>(Tall, o1f, rx2);
  gemm_k<128, 128, 2, 2, F_ACC><<<dim3(64, 8, 1), blk, 0, stream>>>(
      rx2, g2Ub + 2L * 1024 * 1024, Tall + 2048, nullptr, nullptr, nullptr,
      1024, 1024, 1024, 3072, 0, 0, 0, 0, 0, 0);
  gru_out_k<<<8192, blk, 0, stream>>>(Tall, o1f, g2_bg, (float*)d_out, nullptr);
}